// Round 11
// baseline (147.670 us; speedup 1.0000x reference)
//
#include <hip/hip_runtime.h>
#include <hip/hip_bf16.h>
#include <math.h>

// Problem constants
#define Bsz 256
#define Nsz 8192
#define Dsz 768
#define NROWS 512            // 256 rgb + 256 ir anchors
#define INV_T 14.2857142857f // 1/0.07
#define NT 64                // feature cols per block
#define NCB (Nsz / NT)       // 128 col blocks per bank
#define KC 64                // k-chunk staged in LDS
#define NSTG (Dsz / KC)      // 12 stages

typedef __attribute__((ext_vector_type(4))) float f32x4;
typedef __attribute__((ext_vector_type(8))) short bf16x8;
typedef __attribute__((ext_vector_type(4))) short bf16x4;

__device__ __forceinline__ unsigned short f2bf(float f) {
    union { float f; unsigned u; } x; x.f = f;
    unsigned u = x.u;
    return (unsigned short)((u + 0x7fffu + ((u >> 16) & 1u)) >> 16); // RNE
}
__device__ __forceinline__ float bf2f(unsigned short u) {
    union { unsigned u; float f; } x; x.u = ((unsigned)u) << 16;
    return x.f;
}

// Relaxed barrier: LDS handoff only (lgkmcnt(0)), does NOT drain vmcnt.
__device__ __forceinline__ void barrier_lgkm() {
    asm volatile("s_waitcnt lgkmcnt(0)" ::: "memory");
    __builtin_amdgcn_s_barrier();
    asm volatile("" ::: "memory");
}

// fragment-major A index: A-fragment for (row-block rb, k-chunk kc) is a
// contiguous 1KB run; lane l holds row=rb*16+(l&15), k=kc*32+(l>>4)*8+e
__device__ __forceinline__ int fr_idx(int row, int k) {
    int rb = row >> 4, kc = k >> 5;
    int lane = (((k >> 3) & 3) << 4) | (row & 15);
    return (((rb * 24 + kc) << 6) | lane) * 8 + (k & 7);
}

__device__ __forceinline__ bf16x8 cvt8(float4 a, float4 b) {
    union { bf16x8 v; __hip_bfloat162 h[4]; } r;
    r.h[0] = __float22bfloat162_rn({a.x, a.y});
    r.h[1] = __float22bfloat162_rn({a.z, a.w});
    r.h[2] = __float22bfloat162_rn({b.x, b.y});
    r.h[3] = __float22bfloat162_rn({b.z, b.w});
    return r.v;
}

// ---------------- 1. normalize anchors (both layouts) + invert perms + zero out ----------------
__global__ void k_prep(const float* __restrict__ xrgb, const float* __restrict__ xir,
                       const int* __restrict__ prgb, const int* __restrict__ pir,
                       unsigned short* __restrict__ xrm, unsigned short* __restrict__ xfr,
                       int* __restrict__ inv, float* __restrict__ out) {
    int b = blockIdx.x, t = threadIdx.x;
    if (b == 0 && t < 2) out[t] = 0.0f;          // d_out is poisoned 0xAA each call
    if (b < NROWS) {
        const float* src = (b < Bsz) ? (xrgb + b * Dsz) : (xir + (b - Bsz) * Dsz);
        float v0 = src[t], v1 = src[t + 256], v2 = src[t + 512];
        float ss = v0 * v0 + v1 * v1 + v2 * v2;
        #pragma unroll
        for (int m = 1; m < 64; m <<= 1) ss += __shfl_xor(ss, m);
        __shared__ float w4[4];
        if ((t & 63) == 0) w4[t >> 6] = ss;
        __syncthreads();
        float tot = w4[0] + w4[1] + w4[2] + w4[3];
        float invn = 1.0f / fmaxf(sqrtf(tot), 1e-12f);
        unsigned short b0 = f2bf(v0 * invn), b1 = f2bf(v1 * invn), b2 = f2bf(v2 * invn);
        xrm[b * Dsz + t] = b0;
        xrm[b * Dsz + t + 256] = b1;
        xrm[b * Dsz + t + 512] = b2;
        xfr[fr_idx(b, t)] = b0;
        xfr[fr_idx(b, t + 256)] = b1;
        xfr[fr_idx(b, t + 512)] = b2;
    } else {
        int i = (b - NROWS) * 256 + t;           // 0..16383
        if (i < Nsz) inv[prgb[i]] = i;
        else         inv[Nsz + pir[i - Nsz]] = i - Nsz;
    }
}

// ---------------- 2. big fused GEMM + partial softmax ----------------
__global__ __launch_bounds__(512) void k_big(
    const float* __restrict__ Frgb, const float* __restrict__ Fir,
    const unsigned short* __restrict__ xfr,
    float* __restrict__ part_m, float* __restrict__ part_s) {
    __shared__ short Bs[2][NT * KC];        // 2 x 8 KB, XOR-swizzled
    int bid = blockIdx.x;                   // 0..255
    int bank = bid >> 7;
    int cb = bid & (NCB - 1);
    const float* F = bank ? Fir : Frgb;
    int t = threadIdx.x;
    int w = t >> 6, lane = t & 63, lr = lane & 15, lg = lane >> 4;

    // staging coords: thread t loads col=t>>3, k=(t&7)*8 .. +7 (coalesced)
    int scol = t >> 3, sj = t & 7;
    const float* sbase = F + (long)(cb * NT + scol) * Dsz + sj * 8;
    int swidx = scol * 64 + ((sj * 8) ^ ((scol & 7) << 3));   // swizzled short index

    f32x4 acc[4][4] = {};

    // 2-deep chunk prefetch slots
    float4 u0 = *(const float4*)sbase;
    float4 v0 = *(const float4*)(sbase + 4);
    float4 u1 = *(const float4*)(sbase + KC);
    float4 v1 = *(const float4*)(sbase + KC + 4);
    *(bf16x8*)&Bs[0][swidx] = cvt8(u0, v0);      // chunk 0 -> buf 0
    barrier_lgkm();

    // A-fragment rotating prefetch (global/L2)
    bf16x8 a0[4], a1[4];
    #pragma unroll
    for (int rf = 0; rf < 4; ++rf)
        a0[rf] = *(const bf16x8*)&xfr[((((w * 4 + rf) * 24 + 0) << 6) | lane) * 8];

    for (int s = 0; s < NSTG; ++s) {
        // issue chunk s+2 loads (HBM) into slot s&1 — stay in flight across barriers
        if (s + 2 < NSTG) {
            const float* p = sbase + (s + 2) * KC;
            if ((s & 1) == 0) { u0 = *(const float4*)p; v0 = *(const float4*)(p + 4); }
            else              { u1 = *(const float4*)p; v1 = *(const float4*)(p + 4); }
        }
        const short* B0 = Bs[s & 1];
        // ---- half 0: kc = 2s, uses a0; prefetch a1 = frags(2s+1)
        {
            int kcn = s * 2 + 1;
            #pragma unroll
            for (int rf = 0; rf < 4; ++rf)
                a1[rf] = *(const bf16x8*)&xfr[((((w * 4 + rf) * 24 + kcn) << 6) | lane) * 8];
            bf16x8 bfr[4];
            #pragma unroll
            for (int cf = 0; cf < 4; ++cf) {
                int col = cf * 16 + lr;
                int kloc = lg * 8;
                bfr[cf] = *(const bf16x8*)&B0[col * 64 + (kloc ^ ((col & 7) << 3))];
            }
            #pragma unroll
            for (int rf = 0; rf < 4; ++rf)
                #pragma unroll
                for (int cf = 0; cf < 4; ++cf)
                    acc[rf][cf] = __builtin_amdgcn_mfma_f32_16x16x32_bf16(a0[rf], bfr[cf], acc[rf][cf], 0, 0, 0);
        }
        // ---- half 1: kc = 2s+1, uses a1; prefetch a0 = frags(2s+2)
        {
            int kcn = s * 2 + 2;
            if (kcn < 2 * NSTG) {
                #pragma unroll
                for (int rf = 0; rf < 4; ++rf)
                    a0[rf] = *(const bf16x8*)&xfr[((((w * 4 + rf) * 24 + kcn) << 6) | lane) * 8];
            }
            bf16x8 bfr[4];
            #pragma unroll
            for (int cf = 0; cf < 4; ++cf) {
                int col = cf * 16 + lr;
                int kloc = 32 + lg * 8;
                bfr[cf] = *(const bf16x8*)&B0[col * 64 + (kloc ^ ((col & 7) << 3))];
            }
            #pragma unroll
            for (int rf = 0; rf < 4; ++rf)
                #pragma unroll
                for (int cf = 0; cf < 4; ++cf)
                    acc[rf][cf] = __builtin_amdgcn_mfma_f32_16x16x32_bf16(a1[rf], bfr[cf], acc[rf][cf], 0, 0, 0);
        }
        // write chunk s+1 (loaded a full stage ago) into the other buffer
        if (s + 1 < NSTG) {
            if (((s + 1) & 1) == 0) *(bf16x8*)&Bs[0][swidx] = cvt8(u0, v0);
            else                    *(bf16x8*)&Bs[1][swidx] = cvt8(u1, v1);
        }
        barrier_lgkm();
    }

    // per-row partial max + sumexp over this block's 64 cols
    // part layout: [bank][row][cb] so combine reads are coalesced
    #pragma unroll
    for (int rf = 0; rf < 4; ++rf) {
        #pragma unroll
        for (int reg = 0; reg < 4; ++reg) {
            float p0 = acc[rf][0][reg] * INV_T, p1 = acc[rf][1][reg] * INV_T;
            float p2 = acc[rf][2][reg] * INV_T, p3 = acc[rf][3][reg] * INV_T;
            float mx = fmaxf(fmaxf(p0, p1), fmaxf(p2, p3));
            mx = fmaxf(mx, __shfl_xor(mx, 1));
            mx = fmaxf(mx, __shfl_xor(mx, 2));
            mx = fmaxf(mx, __shfl_xor(mx, 4));
            mx = fmaxf(mx, __shfl_xor(mx, 8));
            float sum = __expf(p0 - mx) + __expf(p1 - mx) + __expf(p2 - mx) + __expf(p3 - mx);
            sum += __shfl_xor(sum, 1); sum += __shfl_xor(sum, 2);
            sum += __shfl_xor(sum, 4); sum += __shfl_xor(sum, 8);
            if (lr == 0) {
                int row = w * 64 + rf * 16 + lg * 4 + reg;   // m89-verified C/D layout
                long o = (long)(bank * NROWS + row) * NCB + cb;
                part_m[o] = mx;
                part_s[o] = sum;
            }
        }
    }
}

// ---------------- 3. combine partials + positive dot + final atomic reduce ----------------
__global__ void k_combine(const float* __restrict__ part_m, const float* __restrict__ part_s,
                          const float* __restrict__ Frgb, const float* __restrict__ Fir,
                          const int* __restrict__ trgb, const int* __restrict__ tir,
                          const unsigned short* __restrict__ xrm, const int* __restrict__ inv,
                          float* __restrict__ out) {
    int gw = (blockIdx.x * blockDim.x + threadIdx.x) >> 6;  // 0..1023
    int lane = threadIdx.x & 63;
    int wl = threadIdx.x >> 6;                               // wave in block (0..3)
    int bank = gw >> 9, r = gw & 511;
    const float* pm = part_m + (long)(bank * NROWS + r) * NCB;
    const float* ps = part_s + (long)(bank * NROWS + r) * NCB;
    float m1 = pm[lane], m2 = pm[lane + 64];
    float s1 = ps[lane], s2 = ps[lane + 64];
    float m = fmaxf(m1, m2);
    float s = s1 * __expf(m1 - m) + s2 * __expf(m2 - m);
    #pragma unroll
    for (int mm = 32; mm; mm >>= 1) {
        float om = __shfl_xor(m, mm), os = __shfl_xor(s, mm);
        float nm = fmaxf(m, om);
        s = s * __expf(m - nm) + os * __expf(om - nm);
        m = nm;
    }
    // positive logit: dot(x[r], F[j]) with j = inv_perm[target]
    int tgt = (r < Bsz) ? trgb[r] : tir[r - Bsz];
    int j = inv[bank * Nsz + tgt];
    const float* frow = (bank ? Fir : Frgb) + (long)j * Dsz;
    const unsigned short* xrow = xrm + r * Dsz;
    float d = 0.0f;
    #pragma unroll
    for (int p = 0; p < 3; ++p) {
        int k = p * 256 + lane * 4;
        bf16x4 xv = *(const bf16x4*)&xrow[k];
        float4 fv = *(const float4*)&frow[k];
        d += bf2f((unsigned short)xv[0]) * fv.x + bf2f((unsigned short)xv[1]) * fv.y
           + bf2f((unsigned short)xv[2]) * fv.z + bf2f((unsigned short)xv[3]) * fv.w;
    }
    #pragma unroll
    for (int mm = 1; mm < 64; mm <<= 1) d += __shfl_xor(d, mm);

    __shared__ float red[4];
    if (lane == 0) red[wl] = (m + __logf(s)) - d * INV_T;
    __syncthreads();
    if (threadIdx.x == 0) {
        // all 4 rows of this block share one output segment:
        // seg = bank ^ (r >= 256): 0 -> loss_contr, 1 -> loss_contr_cross
        int seg = bank ^ ((r >= Bsz) ? 1 : 0);
        float tot = (red[0] + red[1] + red[2] + red[3]) * (1.0f / 256.0f);
        atomicAdd(&out[seg], tot);
    }
}

extern "C" void kernel_launch(void* const* d_in, const int* in_sizes, int n_in,
                              void* d_out, int out_size, void* d_ws, size_t ws_size,
                              hipStream_t stream) {
    const float* in_rgb = (const float*)d_in[0];
    const float* in_ir  = (const float*)d_in[1];
    const int*   t_rgb  = (const int*)d_in[2];
    const int*   t_ir   = (const int*)d_in[3];
    const float* F_rgb  = (const float*)d_in[4];
    const float* F_ir   = (const float*)d_in[5];
    const int*   p_rgb  = (const int*)d_in[6];
    const int*   p_ir   = (const int*)d_in[7];
    float* out = (float*)d_out;
    char* ws = (char*)d_ws;

    unsigned short* xrm = (unsigned short*)ws;                 // 786432 B
    unsigned short* xfr = (unsigned short*)(ws + 786432);      // 786432 B
    int*   inv    = (int*)  (ws + 1572864);                    // 65536 B
    float* part_m = (float*)(ws + 1638400);                    // 524288 B
    float* part_s = (float*)(ws + 2162688);                    // 524288 B

    k_prep   <<<NROWS + 64, 256, 0, stream>>>(in_rgb, in_ir, p_rgb, p_ir, xrm, xfr, inv, out);
    // DIAGNOSTIC ROUND: k_big launched TWICE (identical args; deterministic, so
    // the second pass writes identical part values — output unchanged).
    // dur_us(this round) - 124.4 ≈ k_big duration + ~2us graph-node gap.
    k_big    <<<2 * NCB, 512, 0, stream>>>(F_rgb, F_ir, xfr, part_m, part_s);
    k_big    <<<2 * NCB, 512, 0, stream>>>(F_rgb, F_ir, xfr, part_m, part_s);
    k_combine<<<256, 256, 0, stream>>>(part_m, part_s, F_rgb, F_ir, t_rgb, t_ir, xrm, inv, out);
}

// Round 12
// 123.787 us; speedup vs baseline: 1.1929x; 1.1929x over previous
//
#include <hip/hip_runtime.h>
#include <hip/hip_bf16.h>
#include <math.h>

// Problem constants
#define Bsz 256
#define Nsz 8192
#define Dsz 768
#define NROWS 512            // 256 rgb + 256 ir anchors
#define INV_T 14.2857142857f // 1/0.07
#define NT 64                // feature cols per block
#define NCB (Nsz / NT)       // 128 col blocks per bank
#define KC 64                // k-chunk staged in LDS
#define NSTG (Dsz / KC)      // 12 stages

typedef __attribute__((ext_vector_type(4))) float f32x4;
typedef __attribute__((ext_vector_type(8))) short bf16x8;
typedef __attribute__((ext_vector_type(4))) short bf16x4;

__device__ __forceinline__ unsigned short f2bf(float f) {
    union { float f; unsigned u; } x; x.f = f;
    unsigned u = x.u;
    return (unsigned short)((u + 0x7fffu + ((u >> 16) & 1u)) >> 16); // RNE
}
__device__ __forceinline__ float bf2f(unsigned short u) {
    union { unsigned u; float f; } x; x.u = ((unsigned)u) << 16;
    return x.f;
}

// Relaxed barrier: LDS handoff only (lgkmcnt(0)), does NOT drain vmcnt.
__device__ __forceinline__ void barrier_lgkm() {
    asm volatile("s_waitcnt lgkmcnt(0)" ::: "memory");
    __builtin_amdgcn_s_barrier();
    asm volatile("" ::: "memory");
}

// fragment-major A index: A-fragment for (row-block rb, k-chunk kc) is a
// contiguous 1KB run; lane l holds row=rb*16+(l&15), k=kc*32+(l>>4)*8+e
__device__ __forceinline__ int fr_idx(int row, int k) {
    int rb = row >> 4, kc = k >> 5;
    int lane = (((k >> 3) & 3) << 4) | (row & 15);
    return (((rb * 24 + kc) << 6) | lane) * 8 + (k & 7);
}

__device__ __forceinline__ bf16x8 cvt8(float4 a, float4 b) {
    union { bf16x8 v; __hip_bfloat162 h[4]; } r;
    r.h[0] = __float22bfloat162_rn({a.x, a.y});
    r.h[1] = __float22bfloat162_rn({a.z, a.w});
    r.h[2] = __float22bfloat162_rn({b.x, b.y});
    r.h[3] = __float22bfloat162_rn({b.z, b.w});
    return r.v;
}

// ---------------- 1. normalize anchors (both layouts) + invert perms + zero out ----------------
__global__ void k_prep(const float* __restrict__ xrgb, const float* __restrict__ xir,
                       const int* __restrict__ prgb, const int* __restrict__ pir,
                       unsigned short* __restrict__ xrm, unsigned short* __restrict__ xfr,
                       int* __restrict__ inv, float* __restrict__ out) {
    int b = blockIdx.x, t = threadIdx.x;
    if (b == 0 && t < 2) out[t] = 0.0f;          // d_out is poisoned 0xAA each call
    if (b < NROWS) {
        const float* src = (b < Bsz) ? (xrgb + b * Dsz) : (xir + (b - Bsz) * Dsz);
        float v0 = src[t], v1 = src[t + 256], v2 = src[t + 512];
        float ss = v0 * v0 + v1 * v1 + v2 * v2;
        #pragma unroll
        for (int m = 1; m < 64; m <<= 1) ss += __shfl_xor(ss, m);
        __shared__ float w4[4];
        if ((t & 63) == 0) w4[t >> 6] = ss;
        __syncthreads();
        float tot = w4[0] + w4[1] + w4[2] + w4[3];
        float invn = 1.0f / fmaxf(sqrtf(tot), 1e-12f);
        unsigned short b0 = f2bf(v0 * invn), b1 = f2bf(v1 * invn), b2 = f2bf(v2 * invn);
        xrm[b * Dsz + t] = b0;
        xrm[b * Dsz + t + 256] = b1;
        xrm[b * Dsz + t + 512] = b2;
        xfr[fr_idx(b, t)] = b0;
        xfr[fr_idx(b, t + 256)] = b1;
        xfr[fr_idx(b, t + 512)] = b2;
    } else {
        int i = (b - NROWS) * 256 + t;           // 0..16383
        if (i < Nsz) inv[prgb[i]] = i;
        else         inv[Nsz + pir[i - Nsz]] = i - Nsz;
    }
}

// ---------------- 2. big fused GEMM + partial softmax ----------------
// Row-split restructure: 512 blocks (bank x rowhalf x cb), 256 threads (4 waves),
// 2 blocks/CU co-resident for TLP: barriers of one block overlap the other's
// compute; in-flight staging doubles to 64KB/CU.
__global__ __launch_bounds__(256, 2) void k_big(
    const float* __restrict__ Frgb, const float* __restrict__ Fir,
    const unsigned short* __restrict__ xfr,
    float* __restrict__ part_m, float* __restrict__ part_s) {
    __shared__ short Bs[2][NT * KC];        // 2 x 8 KB, XOR-swizzled
    int bid = blockIdx.x;                   // 0..511
    int bank = bid >> 8;
    int rh   = (bid >> 7) & 1;              // row half (0: rows 0-255, 1: 256-511)
    int cb   = bid & (NCB - 1);
    const float* F = bank ? Fir : Frgb;
    int t = threadIdx.x;
    int w = t >> 6, lane = t & 63, lr = lane & 15, lg = lane >> 4;

    // staging coords: thread t loads col=t>>2, k=(t&3)*16 .. +15 (4 x float4)
    int scol = t >> 2, sj = t & 3;
    const float* sbase = F + (long)(cb * NT + scol) * Dsz + sj * 16;
    int sw0 = scol * 64 + ((sj * 16)     ^ ((scol & 7) << 3));   // swizzled short idx, group 0
    int sw1 = scol * 64 + ((sj * 16 + 8) ^ ((scol & 7) << 3));   // group 1

    f32x4 acc[4][4] = {};

    // 2-deep chunk prefetch slots (4 x float4 each; all indices static)
    float4 u0[4], u1[4];
    #pragma unroll
    for (int j = 0; j < 4; ++j) u0[j] = *(const float4*)(sbase + j * 4);
    #pragma unroll
    for (int j = 0; j < 4; ++j) u1[j] = *(const float4*)(sbase + KC + j * 4);
    *(bf16x8*)&Bs[0][sw0] = cvt8(u0[0], u0[1]);   // chunk 0 -> buf 0
    *(bf16x8*)&Bs[0][sw1] = cvt8(u0[2], u0[3]);
    barrier_lgkm();

    // A-fragment rotating prefetch (global/L2); rb base = rowhalf*16 + w*4
    int rbb = rh * 16 + w * 4;
    bf16x8 a0[4], a1[4];
    #pragma unroll
    for (int rf = 0; rf < 4; ++rf)
        a0[rf] = *(const bf16x8*)&xfr[((((rbb + rf) * 24 + 0) << 6) | lane) * 8];

    for (int s = 0; s < NSTG; ++s) {
        // issue chunk s+2 loads (HBM) into slot s&1 — stay in flight across barriers
        if (s + 2 < NSTG) {
            const float* p = sbase + (s + 2) * KC;
            if ((s & 1) == 0) {
                #pragma unroll
                for (int j = 0; j < 4; ++j) u0[j] = *(const float4*)(p + j * 4);
            } else {
                #pragma unroll
                for (int j = 0; j < 4; ++j) u1[j] = *(const float4*)(p + j * 4);
            }
        }
        const short* B0 = Bs[s & 1];
        // ---- half 0: kc = 2s, uses a0; prefetch a1 = frags(2s+1)
        {
            int kcn = s * 2 + 1;
            #pragma unroll
            for (int rf = 0; rf < 4; ++rf)
                a1[rf] = *(const bf16x8*)&xfr[((((rbb + rf) * 24 + kcn) << 6) | lane) * 8];
            bf16x8 bfr[4];
            #pragma unroll
            for (int cf = 0; cf < 4; ++cf) {
                int col = cf * 16 + lr;
                int kloc = lg * 8;
                bfr[cf] = *(const bf16x8*)&B0[col * 64 + (kloc ^ ((col & 7) << 3))];
            }
            #pragma unroll
            for (int rf = 0; rf < 4; ++rf)
                #pragma unroll
                for (int cf = 0; cf < 4; ++cf)
                    acc[rf][cf] = __builtin_amdgcn_mfma_f32_16x16x32_bf16(a0[rf], bfr[cf], acc[rf][cf], 0, 0, 0);
        }
        // ---- half 1: kc = 2s+1, uses a1; prefetch a0 = frags(2s+2)
        {
            int kcn = s * 2 + 2;
            if (kcn < 2 * NSTG) {
                #pragma unroll
                for (int rf = 0; rf < 4; ++rf)
                    a0[rf] = *(const bf16x8*)&xfr[((((rbb + rf) * 24 + kcn) << 6) | lane) * 8];
            }
            bf16x8 bfr[4];
            #pragma unroll
            for (int cf = 0; cf < 4; ++cf) {
                int col = cf * 16 + lr;
                int kloc = 32 + lg * 8;
                bfr[cf] = *(const bf16x8*)&B0[col * 64 + (kloc ^ ((col & 7) << 3))];
            }
            #pragma unroll
            for (int rf = 0; rf < 4; ++rf)
                #pragma unroll
                for (int cf = 0; cf < 4; ++cf)
                    acc[rf][cf] = __builtin_amdgcn_mfma_f32_16x16x32_bf16(a1[rf], bfr[cf], acc[rf][cf], 0, 0, 0);
        }
        // write chunk s+1 (loaded a full stage ago) into the other buffer
        if (s + 1 < NSTG) {
            if (((s + 1) & 1) == 0) {
                *(bf16x8*)&Bs[0][sw0] = cvt8(u0[0], u0[1]);
                *(bf16x8*)&Bs[0][sw1] = cvt8(u0[2], u0[3]);
            } else {
                *(bf16x8*)&Bs[1][sw0] = cvt8(u1[0], u1[1]);
                *(bf16x8*)&Bs[1][sw1] = cvt8(u1[2], u1[3]);
            }
        }
        barrier_lgkm();
    }

    // per-row partial max + sumexp over this block's 64 cols
    // part layout: [bank][row][cb] so combine reads are coalesced
    #pragma unroll
    for (int rf = 0; rf < 4; ++rf) {
        #pragma unroll
        for (int reg = 0; reg < 4; ++reg) {
            float p0 = acc[rf][0][reg] * INV_T, p1 = acc[rf][1][reg] * INV_T;
            float p2 = acc[rf][2][reg] * INV_T, p3 = acc[rf][3][reg] * INV_T;
            float mx = fmaxf(fmaxf(p0, p1), fmaxf(p2, p3));
            mx = fmaxf(mx, __shfl_xor(mx, 1));
            mx = fmaxf(mx, __shfl_xor(mx, 2));
            mx = fmaxf(mx, __shfl_xor(mx, 4));
            mx = fmaxf(mx, __shfl_xor(mx, 8));
            float sum = __expf(p0 - mx) + __expf(p1 - mx) + __expf(p2 - mx) + __expf(p3 - mx);
            sum += __shfl_xor(sum, 1); sum += __shfl_xor(sum, 2);
            sum += __shfl_xor(sum, 4); sum += __shfl_xor(sum, 8);
            if (lr == 0) {
                int row = rh * 256 + w * 64 + rf * 16 + lg * 4 + reg;  // m89-verified C/D layout
                long o = (long)(bank * NROWS + row) * NCB + cb;
                part_m[o] = mx;
                part_s[o] = sum;
            }
        }
    }
}

// ---------------- 3. combine partials + positive dot + final atomic reduce ----------------
__global__ void k_combine(const float* __restrict__ part_m, const float* __restrict__ part_s,
                          const float* __restrict__ Frgb, const float* __restrict__ Fir,
                          const int* __restrict__ trgb, const int* __restrict__ tir,
                          const unsigned short* __restrict__ xrm, const int* __restrict__ inv,
                          float* __restrict__ out) {
    int gw = (blockIdx.x * blockDim.x + threadIdx.x) >> 6;  // 0..1023
    int lane = threadIdx.x & 63;
    int wl = threadIdx.x >> 6;                               // wave in block (0..3)
    int bank = gw >> 9, r = gw & 511;
    const float* pm = part_m + (long)(bank * NROWS + r) * NCB;
    const float* ps = part_s + (long)(bank * NROWS + r) * NCB;
    float m1 = pm[lane], m2 = pm[lane + 64];
    float s1 = ps[lane], s2 = ps[lane + 64];
    float m = fmaxf(m1, m2);
    float s = s1 * __expf(m1 - m) + s2 * __expf(m2 - m);
    #pragma unroll
    for (int mm = 32; mm; mm >>= 1) {
        float om = __shfl_xor(m, mm), os = __shfl_xor(s, mm);
        float nm = fmaxf(m, om);
        s = s * __expf(m - nm) + os * __expf(om - nm);
        m = nm;
    }
    // positive logit: dot(x[r], F[j]) with j = inv_perm[target]
    int tgt = (r < Bsz) ? trgb[r] : tir[r - Bsz];
    int j = inv[bank * Nsz + tgt];
    const float* frow = (bank ? Fir : Frgb) + (long)j * Dsz;
    const unsigned short* xrow = xrm + r * Dsz;
    float d = 0.0f;
    #pragma unroll
    for (int p = 0; p < 3; ++p) {
        int k = p * 256 + lane * 4;
        bf16x4 xv = *(const bf16x4*)&xrow[k];
        float4 fv = *(const float4*)&frow[k];
        d += bf2f((unsigned short)xv[0]) * fv.x + bf2f((unsigned short)xv[1]) * fv.y
           + bf2f((unsigned short)xv[2]) * fv.z + bf2f((unsigned short)xv[3]) * fv.w;
    }
    #pragma unroll
    for (int mm = 1; mm < 64; mm <<= 1) d += __shfl_xor(d, mm);

    __shared__ float red[4];
    if (lane == 0) red[wl] = (m + __logf(s)) - d * INV_T;
    __syncthreads();
    if (threadIdx.x == 0) {
        // all 4 rows of this block share one output segment:
        // seg = bank ^ (r >= 256): 0 -> loss_contr, 1 -> loss_contr_cross
        int seg = bank ^ ((r >= Bsz) ? 1 : 0);
        float tot = (red[0] + red[1] + red[2] + red[3]) * (1.0f / 256.0f);
        atomicAdd(&out[seg], tot);
    }
}

extern "C" void kernel_launch(void* const* d_in, const int* in_sizes, int n_in,
                              void* d_out, int out_size, void* d_ws, size_t ws_size,
                              hipStream_t stream) {
    const float* in_rgb = (const float*)d_in[0];
    const float* in_ir  = (const float*)d_in[1];
    const int*   t_rgb  = (const int*)d_in[2];
    const int*   t_ir   = (const int*)d_in[3];
    const float* F_rgb  = (const float*)d_in[4];
    const float* F_ir   = (const float*)d_in[5];
    const int*   p_rgb  = (const int*)d_in[6];
    const int*   p_ir   = (const int*)d_in[7];
    float* out = (float*)d_out;
    char* ws = (char*)d_ws;

    unsigned short* xrm = (unsigned short*)ws;                 // 786432 B
    unsigned short* xfr = (unsigned short*)(ws + 786432);      // 786432 B
    int*   inv    = (int*)  (ws + 1572864);                    // 65536 B
    float* part_m = (float*)(ws + 1638400);                    // 524288 B
    float* part_s = (float*)(ws + 2162688);                    // 524288 B

    k_prep   <<<NROWS + 64, 256, 0, stream>>>(in_rgb, in_ir, p_rgb, p_ir, xrm, xfr, inv, out);
    k_big    <<<4 * NCB, 256, 0, stream>>>(F_rgb, F_ir, xfr, part_m, part_s);
    k_combine<<<256, 256, 0, stream>>>(part_m, part_s, F_rgb, F_ir, t_rgb, t_ir, xrm, inv, out);
}

// Round 13
// 123.312 us; speedup vs baseline: 1.1975x; 1.0039x over previous
//
#include <hip/hip_runtime.h>
#include <hip/hip_bf16.h>
#include <math.h>

// Problem constants
#define Bsz 256
#define Nsz 8192
#define Dsz 768
#define NROWS 512            // 256 rgb + 256 ir anchors
#define INV_T 14.2857142857f // 1/0.07
#define NT 128               // feature cols per block (halves A-read multiplicity)
#define NCB (Nsz / NT)       // 64 col blocks per bank
#define KC 64                // k-chunk staged in LDS
#define NSTG (Dsz / KC)      // 12 stages

typedef __attribute__((ext_vector_type(4))) float f32x4;
typedef __attribute__((ext_vector_type(8))) short bf16x8;
typedef __attribute__((ext_vector_type(4))) short bf16x4;

__device__ __forceinline__ unsigned short f2bf(float f) {
    union { float f; unsigned u; } x; x.f = f;
    unsigned u = x.u;
    return (unsigned short)((u + 0x7fffu + ((u >> 16) & 1u)) >> 16); // RNE
}
__device__ __forceinline__ float bf2f(unsigned short u) {
    union { unsigned u; float f; } x; x.u = ((unsigned)u) << 16;
    return x.f;
}

// Relaxed barrier: LDS handoff only (lgkmcnt(0)), does NOT drain vmcnt.
__device__ __forceinline__ void barrier_lgkm() {
    asm volatile("s_waitcnt lgkmcnt(0)" ::: "memory");
    __builtin_amdgcn_s_barrier();
    asm volatile("" ::: "memory");
}

// fragment-major A index: A-fragment for (row-block rb, k-chunk kc) is a
// contiguous 1KB run; lane l holds row=rb*16+(l&15), k=kc*32+(l>>4)*8+e
__device__ __forceinline__ int fr_idx(int row, int k) {
    int rb = row >> 4, kc = k >> 5;
    int lane = (((k >> 3) & 3) << 4) | (row & 15);
    return (((rb * 24 + kc) << 6) | lane) * 8 + (k & 7);
}

__device__ __forceinline__ bf16x8 cvt8(float4 a, float4 b) {
    union { bf16x8 v; __hip_bfloat162 h[4]; } r;
    r.h[0] = __float22bfloat162_rn({a.x, a.y});
    r.h[1] = __float22bfloat162_rn({a.z, a.w});
    r.h[2] = __float22bfloat162_rn({b.x, b.y});
    r.h[3] = __float22bfloat162_rn({b.z, b.w});
    return r.v;
}

// ---------------- 1. normalize anchors (both layouts) + invert perms + zero out ----------------
__global__ void k_prep(const float* __restrict__ xrgb, const float* __restrict__ xir,
                       const int* __restrict__ prgb, const int* __restrict__ pir,
                       unsigned short* __restrict__ xrm, unsigned short* __restrict__ xfr,
                       int* __restrict__ inv, float* __restrict__ out) {
    int b = blockIdx.x, t = threadIdx.x;
    if (b == 0 && t < 2) out[t] = 0.0f;          // d_out is poisoned 0xAA each call
    if (b < NROWS) {
        const float* src = (b < Bsz) ? (xrgb + b * Dsz) : (xir + (b - Bsz) * Dsz);
        float v0 = src[t], v1 = src[t + 256], v2 = src[t + 512];
        float ss = v0 * v0 + v1 * v1 + v2 * v2;
        #pragma unroll
        for (int m = 1; m < 64; m <<= 1) ss += __shfl_xor(ss, m);
        __shared__ float w4[4];
        if ((t & 63) == 0) w4[t >> 6] = ss;
        __syncthreads();
        float tot = w4[0] + w4[1] + w4[2] + w4[3];
        float invn = 1.0f / fmaxf(sqrtf(tot), 1e-12f);
        unsigned short b0 = f2bf(v0 * invn), b1 = f2bf(v1 * invn), b2 = f2bf(v2 * invn);
        xrm[b * Dsz + t] = b0;
        xrm[b * Dsz + t + 256] = b1;
        xrm[b * Dsz + t + 512] = b2;
        xfr[fr_idx(b, t)] = b0;
        xfr[fr_idx(b, t + 256)] = b1;
        xfr[fr_idx(b, t + 512)] = b2;
    } else {
        int i = (b - NROWS) * 256 + t;           // 0..16383
        if (i < Nsz) inv[prgb[i]] = i;
        else         inv[Nsz + pir[i - Nsz]] = i - Nsz;
    }
}

// ---------------- 2. big fused GEMM + partial softmax ----------------
// NT=128 restructure: 256 blocks (bank x rowhalf x 64 cb), 512 threads (8 waves).
// VMEM traffic: A 100 MB + B 100 MB = 201 MB (was 301 MB at NT=64) — attacks the
// per-CU VMEM-path volume that R4/R6/R12's latency levers never touched.
__global__ __launch_bounds__(512, 1) void k_big(
    const float* __restrict__ Frgb, const float* __restrict__ Fir,
    const unsigned short* __restrict__ xfr,
    float* __restrict__ part_m, float* __restrict__ part_s) {
    __shared__ short Bs[2][NT * KC];        // 2 x 16 KB, XOR-swizzled
    int bid = blockIdx.x;                   // 0..255
    int bank = bid >> 7;
    int rh   = (bid >> 6) & 1;              // row half (0: rows 0-255, 1: 256-511)
    int cb   = bid & (NCB - 1);             // 0..63
    const float* F = bank ? Fir : Frgb;
    int t = threadIdx.x;
    int w = t >> 6, lane = t & 63, lr = lane & 15, lg = lane >> 4;

    // staging coords: thread t loads col=t>>2 (0..127), k=(t&3)*16 .. +15 (4 x float4)
    int scol = t >> 2, sj = t & 3;
    const float* sbase = F + (long)(cb * NT + scol) * Dsz + sj * 16;
    int sw0 = scol * 64 + ((sj * 16)     ^ ((scol & 7) << 3));   // swizzled short idx
    int sw1 = scol * 64 + ((sj * 16 + 8) ^ ((scol & 7) << 3));

    f32x4 acc[2][8] = {};

    // 2-deep chunk prefetch slots (4 x float4 each; static indices)
    float4 u0[4], u1[4];
    #pragma unroll
    for (int j = 0; j < 4; ++j) u0[j] = *(const float4*)(sbase + j * 4);
    #pragma unroll
    for (int j = 0; j < 4; ++j) u1[j] = *(const float4*)(sbase + KC + j * 4);
    *(bf16x8*)&Bs[0][sw0] = cvt8(u0[0], u0[1]);   // chunk 0 -> buf 0
    *(bf16x8*)&Bs[0][sw1] = cvt8(u0[2], u0[3]);
    barrier_lgkm();

    // A-fragment rotating prefetch (global/L2); wave w owns row-blocks rbb, rbb+1
    int rbb = rh * 16 + w * 2;
    bf16x8 a0[2], a1[2];
    #pragma unroll
    for (int rf = 0; rf < 2; ++rf)
        a0[rf] = *(const bf16x8*)&xfr[((((rbb + rf) * 24 + 0) << 6) | lane) * 8];

    for (int s = 0; s < NSTG; ++s) {
        // issue chunk s+2 loads (HBM) into slot s&1 — stay in flight across barriers
        if (s + 2 < NSTG) {
            const float* p = sbase + (s + 2) * KC;
            if ((s & 1) == 0) {
                #pragma unroll
                for (int j = 0; j < 4; ++j) u0[j] = *(const float4*)(p + j * 4);
            } else {
                #pragma unroll
                for (int j = 0; j < 4; ++j) u1[j] = *(const float4*)(p + j * 4);
            }
        }
        const short* B0 = Bs[s & 1];
        // ---- half 0: kc = 2s, uses a0; prefetch a1 = frags(2s+1)
        {
            int kcn = s * 2 + 1;
            #pragma unroll
            for (int rf = 0; rf < 2; ++rf)
                a1[rf] = *(const bf16x8*)&xfr[((((rbb + rf) * 24 + kcn) << 6) | lane) * 8];
            bf16x8 bfr[8];
            #pragma unroll
            for (int cf = 0; cf < 8; ++cf) {
                int col = cf * 16 + lr;
                int kloc = lg * 8;
                bfr[cf] = *(const bf16x8*)&B0[col * 64 + (kloc ^ ((col & 7) << 3))];
            }
            #pragma unroll
            for (int rf = 0; rf < 2; ++rf)
                #pragma unroll
                for (int cf = 0; cf < 8; ++cf)
                    acc[rf][cf] = __builtin_amdgcn_mfma_f32_16x16x32_bf16(a0[rf], bfr[cf], acc[rf][cf], 0, 0, 0);
        }
        // ---- half 1: kc = 2s+1, uses a1; prefetch a0 = frags(2s+2)
        {
            int kcn = s * 2 + 2;
            if (kcn < 2 * NSTG) {
                #pragma unroll
                for (int rf = 0; rf < 2; ++rf)
                    a0[rf] = *(const bf16x8*)&xfr[((((rbb + rf) * 24 + kcn) << 6) | lane) * 8];
            }
            bf16x8 bfr[8];
            #pragma unroll
            for (int cf = 0; cf < 8; ++cf) {
                int col = cf * 16 + lr;
                int kloc = 32 + lg * 8;
                bfr[cf] = *(const bf16x8*)&B0[col * 64 + (kloc ^ ((col & 7) << 3))];
            }
            #pragma unroll
            for (int rf = 0; rf < 2; ++rf)
                #pragma unroll
                for (int cf = 0; cf < 8; ++cf)
                    acc[rf][cf] = __builtin_amdgcn_mfma_f32_16x16x32_bf16(a1[rf], bfr[cf], acc[rf][cf], 0, 0, 0);
        }
        // write chunk s+1 (loaded a full stage ago) into the other buffer
        if (s + 1 < NSTG) {
            if (((s + 1) & 1) == 0) {
                *(bf16x8*)&Bs[0][sw0] = cvt8(u0[0], u0[1]);
                *(bf16x8*)&Bs[0][sw1] = cvt8(u0[2], u0[3]);
            } else {
                *(bf16x8*)&Bs[1][sw0] = cvt8(u1[0], u1[1]);
                *(bf16x8*)&Bs[1][sw1] = cvt8(u1[2], u1[3]);
            }
        }
        barrier_lgkm();
    }

    // per-row partial max + sumexp over this block's 128 cols
    // part layout: [bank][row][cb] (NCB=64) so combine reads are one lane-load
    #pragma unroll
    for (int rf = 0; rf < 2; ++rf) {
        #pragma unroll
        for (int reg = 0; reg < 4; ++reg) {
            float pv[8];
            #pragma unroll
            for (int cf = 0; cf < 8; ++cf) pv[cf] = acc[rf][cf][reg] * INV_T;
            float mx = pv[0];
            #pragma unroll
            for (int cf = 1; cf < 8; ++cf) mx = fmaxf(mx, pv[cf]);
            mx = fmaxf(mx, __shfl_xor(mx, 1));
            mx = fmaxf(mx, __shfl_xor(mx, 2));
            mx = fmaxf(mx, __shfl_xor(mx, 4));
            mx = fmaxf(mx, __shfl_xor(mx, 8));
            float sum = 0.0f;
            #pragma unroll
            for (int cf = 0; cf < 8; ++cf) sum += __expf(pv[cf] - mx);
            sum += __shfl_xor(sum, 1); sum += __shfl_xor(sum, 2);
            sum += __shfl_xor(sum, 4); sum += __shfl_xor(sum, 8);
            if (lr == 0) {
                int row = rh * 256 + (w * 2 + rf) * 16 + lg * 4 + reg;  // m89-verified C/D layout
                long o = (long)(bank * NROWS + row) * NCB + cb;
                part_m[o] = mx;
                part_s[o] = sum;
            }
        }
    }
}

// ---------------- 3. combine partials + positive dot + final atomic reduce ----------------
__global__ void k_combine(const float* __restrict__ part_m, const float* __restrict__ part_s,
                          const float* __restrict__ Frgb, const float* __restrict__ Fir,
                          const int* __restrict__ trgb, const int* __restrict__ tir,
                          const unsigned short* __restrict__ xrm, const int* __restrict__ inv,
                          float* __restrict__ out) {
    int gw = (blockIdx.x * blockDim.x + threadIdx.x) >> 6;  // 0..1023
    int lane = threadIdx.x & 63;
    int wl = threadIdx.x >> 6;                               // wave in block (0..3)
    int bank = gw >> 9, r = gw & 511;
    const float* pm = part_m + (long)(bank * NROWS + r) * NCB;
    const float* ps = part_s + (long)(bank * NROWS + r) * NCB;
    float m = pm[lane];        // NCB == 64: one partial per lane
    float s = ps[lane];
    #pragma unroll
    for (int mm = 32; mm; mm >>= 1) {
        float om = __shfl_xor(m, mm), os = __shfl_xor(s, mm);
        float nm = fmaxf(m, om);
        s = s * __expf(m - nm) + os * __expf(om - nm);
        m = nm;
    }
    // positive logit: dot(x[r], F[j]) with j = inv_perm[target]
    int tgt = (r < Bsz) ? trgb[r] : tir[r - Bsz];
    int j = inv[bank * Nsz + tgt];
    const float* frow = (bank ? Fir : Frgb) + (long)j * Dsz;
    const unsigned short* xrow = xrm + r * Dsz;
    float d = 0.0f;
    #pragma unroll
    for (int p = 0; p < 3; ++p) {
        int k = p * 256 + lane * 4;
        bf16x4 xv = *(const bf16x4*)&xrow[k];
        float4 fv = *(const float4*)&frow[k];
        d += bf2f((unsigned short)xv[0]) * fv.x + bf2f((unsigned short)xv[1]) * fv.y
           + bf2f((unsigned short)xv[2]) * fv.z + bf2f((unsigned short)xv[3]) * fv.w;
    }
    #pragma unroll
    for (int mm = 1; mm < 64; mm <<= 1) d += __shfl_xor(d, mm);

    __shared__ float red[4];
    if (lane == 0) red[wl] = (m + __logf(s)) - d * INV_T;
    __syncthreads();
    if (threadIdx.x == 0) {
        // all 4 rows of this block share one output segment:
        // seg = bank ^ (r >= 256): 0 -> loss_contr, 1 -> loss_contr_cross
        int seg = bank ^ ((r >= Bsz) ? 1 : 0);
        float tot = (red[0] + red[1] + red[2] + red[3]) * (1.0f / 256.0f);
        atomicAdd(&out[seg], tot);
    }
}

extern "C" void kernel_launch(void* const* d_in, const int* in_sizes, int n_in,
                              void* d_out, int out_size, void* d_ws, size_t ws_size,
                              hipStream_t stream) {
    const float* in_rgb = (const float*)d_in[0];
    const float* in_ir  = (const float*)d_in[1];
    const int*   t_rgb  = (const int*)d_in[2];
    const int*   t_ir   = (const int*)d_in[3];
    const float* F_rgb  = (const float*)d_in[4];
    const float* F_ir   = (const float*)d_in[5];
    const int*   p_rgb  = (const int*)d_in[6];
    const int*   p_ir   = (const int*)d_in[7];
    float* out = (float*)d_out;
    char* ws = (char*)d_ws;

    unsigned short* xrm = (unsigned short*)ws;                 // 786432 B
    unsigned short* xfr = (unsigned short*)(ws + 786432);      // 786432 B
    int*   inv    = (int*)  (ws + 1572864);                    // 65536 B
    float* part_m = (float*)(ws + 1638400);                    // 262144 B
    float* part_s = (float*)(ws + 1900544);                    // 262144 B

    k_prep   <<<NROWS + 64, 256, 0, stream>>>(in_rgb, in_ir, p_rgb, p_ir, xrm, xfr, inv, out);
    k_big    <<<4 * NCB, 512, 0, stream>>>(F_rgb, F_ir, xfr, part_m, part_s);
    k_combine<<<256, 256, 0, stream>>>(part_m, part_s, F_rgb, F_ir, t_rgb, t_ir, xrm, inv, out);
}